// Round 2
// baseline (750.909 us; speedup 1.0000x reference)
//
#include <hip/hip_runtime.h>

// FM-CTR forward: ONE full wave (64 lanes) per batch sample.
// Each lane owns 2 of the 128 embedding dims (float2 per gather row,
// 64 lanes x 8B = 512B fully-coalesced single-row request).
// R4: wave-uniform sample id via readfirstlane; gather addresses as
// uniform-base + 32-bit byte offset to force the saddr global-load form
// (one 32-bit VGPR offset per load, no per-lane 64-bit address pairs).
// All 26 gathers issued back-to-back for max memory-level parallelism.

constexpr int N_TABLES  = 26;
constexpr int VOCAB     = 50000;
constexpr int EMBED_DIM = 128;
constexpr int DENSE_DIM = 13;
constexpr int BATCH     = 16384;

__global__ __launch_bounds__(256, 4) void fmctr_kernel(
    const float* __restrict__ dense_x,     // (BATCH, 13)
    const int*   __restrict__ discrete_x,  // (BATCH, 26) int32
    const float* __restrict__ emb,         // (26, 50000, 128)
    const float* __restrict__ dense_w,     // (128, 13)
    const float* __restrict__ dense_b,     // (128,)
    float*       __restrict__ out)         // (BATCH,)
{
    // one wave per sample; b is wave-uniform -> pin to SGPR
    const int b    = __builtin_amdgcn_readfirstlane(
                         (blockIdx.x * 256 + threadIdx.x) >> 6);
    const int lane = threadIdx.x & 63;     // 64 lanes x 2 dims

    // ---- 26 indices: uniform address -> scalar loads ----
    const int* idxp = discrete_x + (long)b * N_TABLES;
    int idx[N_TABLES];
#pragma unroll
    for (int t = 0; t < N_TABLES; ++t)
        idx[t] = __builtin_amdgcn_readfirstlane(idxp[t]);

    // ---- issue all 26 gathers back-to-back ----
    // byte offset = (t*VOCAB + idx[t]) * 512 + lane*8   (max ~666MB < 2^31)
    const char* embB = (const char*)emb;
    const unsigned loff = (unsigned)lane * 8u;
    float2 v[N_TABLES];
#pragma unroll
    for (int t = 0; t < N_TABLES; ++t) {
        const unsigned off =
            (unsigned)(t * VOCAB + idx[t]) * (unsigned)(EMBED_DIM * 4) + loff;
        v[t] = *(const float2*)(embB + off);
    }

    // ---- accumulate sum and sum-of-squares for this lane's 2 dims ----
    float s0 = 0.f, s1 = 0.f, q0 = 0.f, q1 = 0.f;
#pragma unroll
    for (int t = 0; t < N_TABLES; ++t) {
        s0 += v[t].x;          s1 += v[t].y;
        q0 += v[t].x * v[t].x; q1 += v[t].y * v[t].y;
    }

    // ---- dense embedding for dims j0 = lane*2, j0+1 (tiny inline GEMV) ----
    float xv[DENSE_DIM];
    const float* xp = dense_x + (long)b * DENSE_DIM;
#pragma unroll
    for (int k = 0; k < DENSE_DIM; ++k) xv[k] = xp[k];

    const int j0 = lane * 2;
    const float* w0 = dense_w + (long)j0 * DENSE_DIM;   // row j0, then row j0+1
    float d0 = dense_b[j0], d1 = dense_b[j0 + 1];
#pragma unroll
    for (int k = 0; k < DENSE_DIM; ++k) {
        d0 += xv[k] * w0[k];
        d1 += xv[k] * w0[DENSE_DIM + k];
    }

    float fm = 0.f;
    {
        const float ss0 = s0 + d0, qq0 = q0 + d0 * d0;
        fm += 0.5f * (ss0 * ss0 - qq0);
        const float ss1 = s1 + d1, qq1 = q1 + d1 * d1;
        fm += 0.5f * (ss1 * ss1 - qq1);
    }

    // ---- reduce fm across the 64 lanes of the wave ----
#pragma unroll
    for (int m = 32; m >= 1; m >>= 1)
        fm += __shfl_xor(fm, m, 64);

    if (lane == 0) out[b] = fm;
}

extern "C" void kernel_launch(void* const* d_in, const int* in_sizes, int n_in,
                              void* d_out, int out_size, void* d_ws, size_t ws_size,
                              hipStream_t stream) {
    const float* dense_x    = (const float*)d_in[0];
    const int*   discrete_x = (const int*)  d_in[1];
    const float* emb        = (const float*)d_in[2];
    const float* dense_w    = (const float*)d_in[3];
    const float* dense_b    = (const float*)d_in[4];
    float*       out        = (float*)d_out;

    // 256 threads = 4 waves = 4 samples per block
    const int blocks = (BATCH * 64) / 256;   // 4096
    fmctr_kernel<<<blocks, 256, 0, stream>>>(dense_x, discrete_x, emb,
                                             dense_w, dense_b, out);
}

// Round 4
// 749.334 us; speedup vs baseline: 1.0021x; 1.0021x over previous
//
#include <hip/hip_runtime.h>

// FM-CTR forward: ONE full wave (64 lanes) per batch sample.
// Each lane owns 2 of the 128 embedding dims (float2 per gather row).
// R5 (resubmit): (a) all 26 indices fetched in ONE coalesced request
//     (lanes 0..25) and broadcast to SGPRs via v_readlane -> gathers are
//     pure saddr form with a single shared VGPR lane-offset; (b) dense_x
//     fetched the same way (lanes 0..12); (c) VGPR budget ~62 ->
//     __launch_bounds__(256,8) for 8 waves/SIMD (2x occupancy) to deepen
//     the chip-wide request queue for DRAM bank-level parallelism.

constexpr int N_TABLES  = 26;
constexpr int VOCAB     = 50000;
constexpr int EMBED_DIM = 128;
constexpr int DENSE_DIM = 13;
constexpr int BATCH     = 16384;

__global__ __launch_bounds__(256, 8) void fmctr_kernel(
    const float* __restrict__ dense_x,     // (BATCH, 13)
    const int*   __restrict__ discrete_x,  // (BATCH, 26) int32
    const float* __restrict__ emb,         // (26, 50000, 128)
    const float* __restrict__ dense_w,     // (128, 13)
    const float* __restrict__ dense_b,     // (128,)
    float*       __restrict__ out)         // (BATCH,)
{
    // one wave per sample; b is wave-uniform -> pin to SGPR
    const int b    = __builtin_amdgcn_readfirstlane(
                         (blockIdx.x * 256 + threadIdx.x) >> 6);
    const int lane = threadIdx.x & 63;     // 64 lanes x 2 dims

    // ---- fetch 26 indices + 13 dense features in TWO coalesced requests ----
    int   myidx = 0;
    float myx   = 0.f;
    if (lane < N_TABLES)  myidx = discrete_x[(long)b * N_TABLES + lane];
    if (lane < DENSE_DIM) myx   = dense_x[(long)b * DENSE_DIM + lane];

    // broadcast indices into SGPRs (readlane with literal lane index)
    int idx[N_TABLES];
#pragma unroll
    for (int t = 0; t < N_TABLES; ++t)
        idx[t] = __builtin_amdgcn_readlane(myidx, t);

    // broadcast dense features into SGPRs
    float xv[DENSE_DIM];
#pragma unroll
    for (int k = 0; k < DENSE_DIM; ++k)
        xv[k] = __builtin_bit_cast(float,
                    __builtin_amdgcn_readlane(__builtin_bit_cast(int, myx), k));

    // ---- issue all 26 gathers back-to-back (scalar base + shared lane off) ----
    const char* embB = (const char*)emb;
    const unsigned loff = (unsigned)lane * 8u;   // the ONLY vector offset
    float2 v[N_TABLES];
#pragma unroll
    for (int t = 0; t < N_TABLES; ++t) {
        const unsigned off =
            (unsigned)(t * VOCAB + idx[t]) * (unsigned)(EMBED_DIM * 4);
        v[t] = *(const float2*)(embB + off + loff);
    }

    // ---- accumulate sum and sum-of-squares for this lane's 2 dims ----
    float s0 = 0.f, s1 = 0.f, q0 = 0.f, q1 = 0.f;
#pragma unroll
    for (int t = 0; t < N_TABLES; ++t) {
        s0 += v[t].x;          s1 += v[t].y;
        q0 += v[t].x * v[t].x; q1 += v[t].y * v[t].y;
    }

    // ---- dense embedding for dims j0 = lane*2, j0+1 (tiny inline GEMV) ----
    const int j0 = lane * 2;
    const float* w0 = dense_w + (long)j0 * DENSE_DIM;   // row j0, then row j0+1
    float d0 = dense_b[j0], d1 = dense_b[j0 + 1];
#pragma unroll
    for (int k = 0; k < DENSE_DIM; ++k) {
        d0 += xv[k] * w0[k];
        d1 += xv[k] * w0[DENSE_DIM + k];
    }

    float fm = 0.f;
    {
        const float ss0 = s0 + d0, qq0 = q0 + d0 * d0;
        fm += 0.5f * (ss0 * ss0 - qq0);
        const float ss1 = s1 + d1, qq1 = q1 + d1 * d1;
        fm += 0.5f * (ss1 * ss1 - qq1);
    }

    // ---- reduce fm across the 64 lanes of the wave ----
#pragma unroll
    for (int m = 32; m >= 1; m >>= 1)
        fm += __shfl_xor(fm, m, 64);

    if (lane == 0) out[b] = fm;
}

extern "C" void kernel_launch(void* const* d_in, const int* in_sizes, int n_in,
                              void* d_out, int out_size, void* d_ws, size_t ws_size,
                              hipStream_t stream) {
    const float* dense_x    = (const float*)d_in[0];
    const int*   discrete_x = (const int*)  d_in[1];
    const float* emb        = (const float*)d_in[2];
    const float* dense_w    = (const float*)d_in[3];
    const float* dense_b    = (const float*)d_in[4];
    float*       out        = (float*)d_out;

    // 256 threads = 4 waves = 4 samples per block
    const int blocks = (BATCH * 64) / 256;   // 4096
    fmctr_kernel<<<blocks, 256, 0, stream>>>(dense_x, discrete_x, emb,
                                             dense_w, dense_b, out);
}

// Round 5
// 735.608 us; speedup vs baseline: 1.0208x; 1.0187x over previous
//
#include <hip/hip_runtime.h>

// FM-CTR forward: ONE full wave (64 lanes) per batch sample.
// Each lane owns 2 of the 128 embedding dims (float2 per gather row).
// R6: (a) gathers are NON-TEMPORAL (nt) loads -> no L2/L3 allocation for
//     this zero-reuse 218MB stream (tests cache-thrash-limited theory);
//     (b) staging reduced to 13-row chunks (26 VGPRs) so the kernel is
//     genuinely spill-free under __launch_bounds__(256,8) (64-VGPR cap)
//     -> true 8 waves/SIMD, 104 gathers in flight per SIMD.
// Indices fetched in one coalesced request and broadcast to SGPRs via
// readlane; gathers are saddr-form with a single shared VGPR lane offset.

constexpr int N_TABLES  = 26;
constexpr int VOCAB     = 50000;
constexpr int EMBED_DIM = 128;
constexpr int DENSE_DIM = 13;
constexpr int BATCH     = 16384;
constexpr int CHUNK     = 13;   // gathers staged per chunk (26 VGPRs)

typedef float f32x2 __attribute__((ext_vector_type(2)));

__global__ __launch_bounds__(256, 8) void fmctr_kernel(
    const float* __restrict__ dense_x,     // (BATCH, 13)
    const int*   __restrict__ discrete_x,  // (BATCH, 26) int32
    const float* __restrict__ emb,         // (26, 50000, 128)
    const float* __restrict__ dense_w,     // (128, 13)
    const float* __restrict__ dense_b,     // (128,)
    float*       __restrict__ out)         // (BATCH,)
{
    // one wave per sample; b is wave-uniform -> pin to SGPR
    const int b    = __builtin_amdgcn_readfirstlane(
                         (blockIdx.x * 256 + threadIdx.x) >> 6);
    const int lane = threadIdx.x & 63;     // 64 lanes x 2 dims

    // ---- fetch 26 indices + 13 dense features in TWO coalesced requests ----
    int   myidx = 0;
    float myx   = 0.f;
    if (lane < N_TABLES)  myidx = discrete_x[(long)b * N_TABLES + lane];
    if (lane < DENSE_DIM) myx   = dense_x[(long)b * DENSE_DIM + lane];

    // broadcast indices into SGPRs (readlane with literal lane index)
    int idx[N_TABLES];
#pragma unroll
    for (int t = 0; t < N_TABLES; ++t)
        idx[t] = __builtin_amdgcn_readlane(myidx, t);

    // broadcast dense features into SGPRs
    float xv[DENSE_DIM];
#pragma unroll
    for (int k = 0; k < DENSE_DIM; ++k)
        xv[k] = __builtin_bit_cast(float,
                    __builtin_amdgcn_readlane(__builtin_bit_cast(int, myx), k));

    // ---- gather: 2 chunks of 13 non-temporal 8B loads, saddr form ----
    const char* embB = (const char*)emb;
    const unsigned loff = (unsigned)lane * 8u;   // the ONLY vector offset
    float s0 = 0.f, s1 = 0.f, q0 = 0.f, q1 = 0.f;

#pragma unroll
    for (int c = 0; c < N_TABLES; c += CHUNK) {
        f32x2 v[CHUNK];
#pragma unroll
        for (int j = 0; j < CHUNK; ++j) {
            const int t = c + j;
            const unsigned off =
                (unsigned)(t * VOCAB + idx[t]) * (unsigned)(EMBED_DIM * 4);
            v[j] = __builtin_nontemporal_load(
                       (const f32x2*)(embB + off + loff));
        }
#pragma unroll
        for (int j = 0; j < CHUNK; ++j) {
            s0 += v[j].x;          s1 += v[j].y;
            q0 += v[j].x * v[j].x; q1 += v[j].y * v[j].y;
        }
    }

    // ---- dense embedding for dims j0 = lane*2, j0+1 (tiny inline GEMV) ----
    const int j0 = lane * 2;
    const float* w0 = dense_w + (long)j0 * DENSE_DIM;   // row j0, then row j0+1
    float d0 = dense_b[j0], d1 = dense_b[j0 + 1];
#pragma unroll
    for (int k = 0; k < DENSE_DIM; ++k) {
        d0 += xv[k] * w0[k];
        d1 += xv[k] * w0[DENSE_DIM + k];
    }

    float fm = 0.f;
    {
        const float ss0 = s0 + d0, qq0 = q0 + d0 * d0;
        fm += 0.5f * (ss0 * ss0 - qq0);
        const float ss1 = s1 + d1, qq1 = q1 + d1 * d1;
        fm += 0.5f * (ss1 * ss1 - qq1);
    }

    // ---- reduce fm across the 64 lanes of the wave ----
#pragma unroll
    for (int m = 32; m >= 1; m >>= 1)
        fm += __shfl_xor(fm, m, 64);

    if (lane == 0) out[b] = fm;
}

extern "C" void kernel_launch(void* const* d_in, const int* in_sizes, int n_in,
                              void* d_out, int out_size, void* d_ws, size_t ws_size,
                              hipStream_t stream) {
    const float* dense_x    = (const float*)d_in[0];
    const int*   discrete_x = (const int*)  d_in[1];
    const float* emb        = (const float*)d_in[2];
    const float* dense_w    = (const float*)d_in[3];
    const float* dense_b    = (const float*)d_in[4];
    float*       out        = (float*)d_out;

    // 256 threads = 4 waves = 4 samples per block
    const int blocks = (BATCH * 64) / 256;   // 4096
    fmctr_kernel<<<blocks, 256, 0, stream>>>(dense_x, discrete_x, emb,
                                             dense_w, dense_b, out);
}